// Round 6
// baseline (562.338 us; speedup 1.0000x reference)
//
#include <hip/hip_runtime.h>
#include <hip/hip_bf16.h>
#include <cstddef>

#define MIN_VALUE_F (-3.402823466e38f)

// B=4, C=64, T=256, D=256, H=4, DK=64, OUT=256, M = B*C*T = 65536

typedef __attribute__((ext_vector_type(8))) __bf16 bfrag;    // MFMA A/B operand (4 VGPR)
typedef __attribute__((ext_vector_type(4))) float f32x4;     // MFMA C/D operand

__device__ __forceinline__ float bf2f(unsigned int u) {
    union { unsigned int i; float f; } v; v.i = u << 16; return v.f;
}
__device__ __forceinline__ unsigned short f2bf(float f) {
    union { float f; unsigned int i; } v; v.f = f;
    return (unsigned short)((v.i + 0x7fffu + ((v.i >> 16) & 1u)) >> 16);
}
__device__ __forceinline__ unsigned int cvt2(float a, float b) {
    __hip_bfloat16 lo = __float2bfloat16(a);
    __hip_bfloat16 hi = __float2bfloat16(b);
    union { __hip_bfloat16 h[2]; unsigned int u; } x;
    x.h[0] = lo; x.h[1] = hi;
    return x.u;
}
__device__ __forceinline__ bfrag negf(bfrag v) {
    union { bfrag b; unsigned int u[4]; } x; x.b = v;
    #pragma unroll
    for (int i = 0; i < 4; ++i) x.u[i] ^= 0x80008000u;
    return x.b;
}

typedef __attribute__((address_space(3))) void lds_void_t;
typedef const __attribute__((address_space(1))) void gmem_void_t;
__device__ __forceinline__ void glds16(const void* g, void* l) {
    __builtin_amdgcn_global_load_lds((gmem_void_t*)g, (lds_void_t*)l, 16, 0, 0);
}

// fragment read from XOR-swizzled row-major 64x64 bf16 tile (row stride 64 ushorts) [attn]
__device__ __forceinline__ bfrag rdfrag(const unsigned short* arr, int row, int slot) {
    const int s = slot ^ (row & 7);
    return *(const bfrag*)&arr[row * 64 + s * 8];
}

// ---------------- Weight prepass: f32 (K=256,N=256) -> bf16 pre-swizzled images ----
// BK=32 layout: per matrix 65536 ushorts = [nb(2)][s(8)][n(128)][ss(4)][j(8)],
// stored k-slot ss holds source slot (ss ^ ((n>>1)&3)); global k = s*32 + slot*8 + j.
__global__ __launch_bounds__(256)
void wprep_kernel(const float* __restrict__ w0, const float* __restrict__ w1,
                  const float* __restrict__ w2, const float* __restrict__ w3,
                  const float* __restrict__ w4, const float* __restrict__ w5,
                  unsigned short* __restrict__ dst)
{
    const int my = blockIdx.y;
    const float* wsrc[6] = {w0, w1, w2, w3, w4, w5};
    const float* w = wsrc[my];
    const int cid = blockIdx.x * 256 + threadIdx.x;   // 0..8191 chunks (16B each)
    const int ss = cid & 3;
    const int n  = (cid >> 2) & 127;
    const int s  = (cid >> 9) & 7;
    const int nb = (cid >> 12) & 1;
    const int nn = nb * 128 + n;
    const int kb = s * 32 + ((ss ^ ((n >> 1) & 3)) << 3);
    unsigned int p[4];
    #pragma unroll
    for (int jj = 0; jj < 4; ++jj) {
        const float a = w[(size_t)(kb + 2 * jj) * 256 + nn];
        const float b = w[(size_t)(kb + 2 * jj + 1) * 256 + nn];
        p[jj] = cvt2(a, b);
    }
    uint4 q; q.x = p[0]; q.y = p[1]; q.z = p[2]; q.w = p[3];
    *(uint4*)&dst[(size_t)my * 65536 + (size_t)cid * 8] = q;
}

// ---------------- Stage 1: complex QKV projection via MFMA ----------------
// 128x128 tile, BK=32, 8 K-steps, double-buffered LDS (2 x 32 KB), ONE barrier/step.
// Per buf (ushorts): A_r [0,4096) A_i [4096,8192) W_r [8192,12288) W_i [12288,16384).
__global__ __launch_bounds__(512, 4)
void proj_mfma(const float* __restrict__ xq_r, const float* __restrict__ xq_i,
               const float* __restrict__ xk_r, const float* __restrict__ xk_i,
               const float* __restrict__ xv_r, const float* __restrict__ xv_i,
               const unsigned short* __restrict__ wimg,
               const float* __restrict__ bq_r, const float* __restrict__ bq_i,
               const float* __restrict__ bk_r, const float* __restrict__ bk_i,
               const float* __restrict__ bv_r, const float* __restrict__ bv_i,
               unsigned short* __restrict__ ws_out)
{
    __shared__ __align__(16) unsigned short SH[32768];   // 64 KB

    const int pz = blockIdx.z;
    const float *xr, *xi, *br_, *bi_;
    if (pz == 0)      { xr = xq_r; xi = xq_i; br_ = bq_r; bi_ = bq_i; }
    else if (pz == 1) { xr = xk_r; xi = xk_i; br_ = bk_r; bi_ = bk_i; }
    else              { xr = xv_r; xi = xv_i; br_ = bv_r; bi_ = bv_i; }
    unsigned short* outr = ws_out + (size_t)pz * 2 * 16777216;
    unsigned short* outi = outr + 16777216;

    const int tid = threadIdx.x;
    const int lane = tid & 63, wv = tid >> 6;
    const int l15 = lane & 15, hi = lane >> 4;
    const int wm = (wv >> 2) * 64, wn = (wv & 3) * 32;
    const int m0 = blockIdx.x * 128;
    const int nb = blockIdx.y;

    const unsigned short* wr_img = wimg + (size_t)pz * 131072 + nb * 32768;
    const unsigned short* wi_img = wr_img + 65536;

    // A staging: 128 rows x 32 k f32 x2 tensors; coalesced: instr covers 8 dense 128B rows
    const int arow = tid >> 3;     // 0..63 (+64 for second instr)
    const int apos = tid & 7;      // 16B chunk within the row's 128B segment
    float4 fr0, fr1, fi0, fi1;

    f32x4 accR[4][2] = {}, accI[4][2] = {};

    auto loadA = [&](int s) {
        const size_t o0 = (size_t)(m0 + arow) * 256 + s * 32 + apos * 4;
        const size_t o1 = (size_t)(m0 + 64 + arow) * 256 + s * 32 + apos * 4;
        fr0 = *(const float4*)(xr + o0);
        fr1 = *(const float4*)(xr + o1);
        fi0 = *(const float4*)(xi + o0);
        fi1 = *(const float4*)(xi + o1);
    };
    auto loadW = [&](int s, int buf) {
        glds16(wr_img + s * 4096 + tid * 8, &SH[buf * 16384 + 8192 + tid * 8]);
        glds16(wi_img + s * 4096 + tid * 8, &SH[buf * 16384 + 12288 + tid * 8]);
    };
    auto writeA = [&](int buf) {
        const int r0 = arow, r1 = 64 + arow;
        const int sw = (apos >> 1) ^ ((r0 >> 1) & 3);      // same for r1 (r1 = r0+64)
        const int hf = (apos & 1) * 4;
        const int i0 = buf * 16384 + r0 * 32 + (sw << 3) + hf;
        const int i1 = buf * 16384 + r1 * 32 + (sw << 3) + hf;
        uint2 a;
        a.x = cvt2(fr0.x, fr0.y); a.y = cvt2(fr0.z, fr0.w);
        *(uint2*)&SH[i0] = a;
        a.x = cvt2(fr1.x, fr1.y); a.y = cvt2(fr1.z, fr1.w);
        *(uint2*)&SH[i1] = a;
        a.x = cvt2(fi0.x, fi0.y); a.y = cvt2(fi0.z, fi0.w);
        *(uint2*)&SH[4096 + i0] = a;
        a.x = cvt2(fi1.x, fi1.y); a.y = cvt2(fi1.z, fi1.w);
        *(uint2*)&SH[4096 + i1] = a;
    };

    loadA(0); loadW(0, 0); writeA(0);
    __syncthreads();

    for (int s = 0; s < 8; ++s) {
        const int b = s & 1;
        if (s < 7) { loadA(s + 1); loadW(s + 1, b ^ 1); }   // into other buffer, no race
        const unsigned short* Ar = &SH[b * 16384];
        const unsigned short* Ai = Ar + 4096;
        const unsigned short* Wr = Ar + 8192;
        const unsigned short* Wi = Ar + 12288;
        bfrag ar[4], ai[4], nai[4];
        #pragma unroll
        for (int mf = 0; mf < 4; ++mf) {
            const int m = wm + mf * 16 + l15;
            const int idx = m * 32 + ((hi ^ ((m >> 1) & 3)) << 3);
            ar[mf] = *(const bfrag*)&Ar[idx];
            ai[mf] = *(const bfrag*)&Ai[idx];
            nai[mf] = negf(ai[mf]);
        }
        #pragma unroll
        for (int nf = 0; nf < 2; ++nf) {
            const int n = wn + nf * 16 + l15;
            const int idx = n * 32 + ((hi ^ ((n >> 1) & 3)) << 3);
            const bfrag brf = *(const bfrag*)&Wr[idx];
            const bfrag bif = *(const bfrag*)&Wi[idx];
            #pragma unroll
            for (int mf = 0; mf < 4; ++mf) {
                accR[mf][nf] = __builtin_amdgcn_mfma_f32_16x16x32_bf16(ar[mf], brf, accR[mf][nf], 0, 0, 0);
                accR[mf][nf] = __builtin_amdgcn_mfma_f32_16x16x32_bf16(nai[mf], bif, accR[mf][nf], 0, 0, 0);
                accI[mf][nf] = __builtin_amdgcn_mfma_f32_16x16x32_bf16(ai[mf], brf, accI[mf][nf], 0, 0, 0);
                accI[mf][nf] = __builtin_amdgcn_mfma_f32_16x16x32_bf16(ar[mf], bif, accI[mf][nf], 0, 0, 0);
            }
        }
        if (s < 7) writeA(b ^ 1);
        __syncthreads();
    }

    // ---- epilogue: bias, stage full bf16 tile in LDS (r @0, i @16384), coalesced store
    const int bc = m0 >> 8, b = bc >> 6, c = bc & 63, t0 = m0 & 255;
    const int rowL = (lane >> 4) << 2;
    #pragma unroll
    for (int nf = 0; nf < 2; ++nf) {
        const int n_loc = wn + nf * 16 + l15;        // 0..127
        const int n_glob = nb * 128 + n_loc;
        const int hs = n_loc >> 6, dk = n_loc & 63;
        const float vbr = br_[n_glob], vbi = bi_[n_glob];
        const float addR = vbr - vbi, addI = vbr + vbi;
        #pragma unroll
        for (int mf = 0; mf < 4; ++mf) {
            const int tr = wm + mf * 16 + rowL;
            #pragma unroll
            for (int r = 0; r < 4; ++r) {
                const int L = hs * 8192 + (tr + r) * 64 + dk;
                SH[L] = f2bf(accR[mf][nf][r] + addR);
                SH[16384 + L] = f2bf(accI[mf][nf][r] + addI);
            }
        }
    }
    __syncthreads();
    const int h0 = nb * 2;
    #pragma unroll
    for (int p = 0; p < 4; ++p) {
        const int L = p * 4096 + tid * 8;
        const int hs2 = L >> 13, tr2 = (L >> 6) & 127, dk2 = L & 63;
        const size_t g = (((size_t)(b * 4 + h0 + hs2) * 256 + (t0 + tr2)) * 64 + c) * 64 + dk2;
        *(uint4*)&outr[g] = *(const uint4*)&SH[L];
        *(uint4*)&outi[g] = *(const uint4*)&SH[16384 + L];
    }
}

// ---------------- Stage 2: fused complex attention per (b,h,t), MFMA (unchanged) ------
__global__ __launch_bounds__(256)
void attn_mfma(const unsigned short* __restrict__ Qg_r, const unsigned short* __restrict__ Qg_i,
               const unsigned short* __restrict__ Kg_r, const unsigned short* __restrict__ Kg_i,
               const unsigned short* __restrict__ Vg_r, const unsigned short* __restrict__ Vg_i,
               const int* __restrict__ mask,
               unsigned short* __restrict__ Xr, unsigned short* __restrict__ Xi)
{
    __shared__ __align__(16) unsigned short sQr[4096], sQi[4096];   // Q, then P
    __shared__ __align__(16) unsigned short sKr[4096], sKi[4096];
    __shared__ __align__(16) unsigned short sVr[4608], sVi[4608];   // V^T, rows padded to 72
    __shared__ int smask[64];

    const int bht = blockIdx.x;
    const int b = bht >> 10;
    const int h = (bht >> 8) & 3;
    const int t = bht & 255;
    const size_t base = (size_t)bht * 4096;
    const int tid = threadIdx.x;
    const int lane = tid & 63, wv = tid >> 6;
    const int l15 = lane & 15, hi = lane >> 4;

    const int ep = (lane & 31) * 2;
    const int dch = wv * 2 + (lane >> 5);
    const unsigned short* vr0p = Vg_r + base + (size_t)ep * 64 + dch * 8;
    const unsigned short* vi0p = Vg_i + base + (size_t)ep * 64 + dch * 8;
    const uint4 vr0 = *(const uint4*)vr0p;
    const uint4 vr1 = *(const uint4*)(vr0p + 64);
    const uint4 vi0 = *(const uint4*)vi0p;
    const uint4 vi1 = *(const uint4*)(vi0p + 64);

    #pragma unroll
    for (int i = 0; i < 2; ++i) {
        const int ch = wv * 128 + i * 64 + lane;
        const int r = ch >> 3, cg = ch & 7;
        const int so = r * 64 + ((cg ^ (r & 7)) << 3);
        const int dofs = (wv * 128 + i * 64) << 3;
        glds16(Qg_r + base + so, &sQr[dofs]);
        glds16(Qg_i + base + so, &sQi[dofs]);
        glds16(Kg_r + base + so, &sKr[dofs]);
        glds16(Kg_i + base + so, &sKi[dofs]);
    }
    if (tid < 64) smask[tid] = mask[b * 64 + tid];

    {
        union { uint4 v; unsigned short s[8]; } ar0, ar1, ai0, ai1;
        ar0.v = vr0; ar1.v = vr1; ai0.v = vi0; ai1.v = vi1;
        #pragma unroll
        for (int j = 0; j < 8; ++j) {
            const int d = dch * 8 + j;
            *(unsigned int*)&sVr[d * 72 + ep] = (unsigned)ar0.s[j] | ((unsigned)ar1.s[j] << 16);
            *(unsigned int*)&sVi[d * 72 + ep] = (unsigned)ai0.s[j] | ((unsigned)ai1.s[j] << 16);
        }
    }
    __syncthreads();

    const int cq = wv * 16 + l15;
    f32x4 aR[4] = {}, aI[4] = {};
    #pragma unroll
    for (int ks = 0; ks < 2; ++ks) {
        const int slot = ks * 4 + hi;
        const bfrag qr = rdfrag(sQr, cq, slot);
        const bfrag qi = rdfrag(sQi, cq, slot);
        const bfrag nqi = negf(qi);
        #pragma unroll
        for (int et = 0; et < 4; ++et) {
            const int re = et * 16 + l15;
            const bfrag kr = rdfrag(sKr, re, slot);
            const bfrag ki = rdfrag(sKi, re, slot);
            aR[et] = __builtin_amdgcn_mfma_f32_16x16x32_bf16(kr, qr, aR[et], 0, 0, 0);
            aR[et] = __builtin_amdgcn_mfma_f32_16x16x32_bf16(ki, qi, aR[et], 0, 0, 0);
            aI[et] = __builtin_amdgcn_mfma_f32_16x16x32_bf16(ki, qr, aI[et], 0, 0, 0);
            aI[et] = __builtin_amdgcn_mfma_f32_16x16x32_bf16(kr, nqi, aI[et], 0, 0, 0);
        }
    }
    __syncthreads();

    const float scale = 0.125f;
    float amp[4][4], ex[4][4];
    float mx = MIN_VALUE_F;
    #pragma unroll
    for (int et = 0; et < 4; ++et) {
        #pragma unroll
        for (int r = 0; r < 4; ++r) {
            const float sr = aR[et][r] * scale;
            const float si = aI[et][r] * scale;
            float a = sqrtf(fmaf(sr, sr, si * si));
            if (smask[et * 16 + hi * 4 + r] == 0) a = MIN_VALUE_F;
            amp[et][r] = a;
            mx = fmaxf(mx, a);
        }
    }
    mx = fmaxf(mx, __shfl_xor(mx, 16, 64));
    mx = fmaxf(mx, __shfl_xor(mx, 32, 64));
    float sm = 0.f;
    #pragma unroll
    for (int et = 0; et < 4; ++et) {
        #pragma unroll
        for (int r = 0; r < 4; ++r) {
            const float e_ = expf(amp[et][r] - mx);
            ex[et][r] = e_; sm += e_;
        }
    }
    sm += __shfl_xor(sm, 16, 64);
    sm += __shfl_xor(sm, 32, 64);

    #pragma unroll
    for (int et = 0; et < 4; ++et) {
        float pr[4], pi[4];
        #pragma unroll
        for (int r = 0; r < 4; ++r) {
            const float w = ex[et][r] * __builtin_amdgcn_rcpf(sm * amp[et][r]);
            pr[r] = w * (aR[et][r] * scale);
            pi[r] = w * (aI[et][r] * scale);
        }
        const int pidx = cq * 64 + ((et * 16 + hi * 4) ^ ((cq & 7) << 3));
        uint2 ur, ui;
        ur.x = cvt2(pr[0], pr[1]); ur.y = cvt2(pr[2], pr[3]);
        ui.x = cvt2(pi[0], pi[1]); ui.y = cvt2(pi[2], pi[3]);
        *(uint2*)&sQr[pidx] = ur;
        *(uint2*)&sQi[pidx] = ui;
    }
    __syncthreads();

    f32x4 xR4[4] = {}, xI4[4] = {};
    #pragma unroll
    for (int ks = 0; ks < 2; ++ks) {
        const int slot = ks * 4 + hi;
        const bfrag pr = rdfrag(sQr, cq, slot);
        const bfrag pi = rdfrag(sQi, cq, slot);
        const bfrag npi = negf(pi);
        #pragma unroll
        for (int dt = 0; dt < 4; ++dt) {
            const int rd = dt * 16 + l15;
            const bfrag vr = *(const bfrag*)&sVr[rd * 72 + ks * 32 + hi * 8];
            const bfrag vi = *(const bfrag*)&sVi[rd * 72 + ks * 32 + hi * 8];
            xR4[dt] = __builtin_amdgcn_mfma_f32_16x16x32_bf16(pr, vr, xR4[dt], 0, 0, 0);
            xR4[dt] = __builtin_amdgcn_mfma_f32_16x16x32_bf16(npi, vi, xR4[dt], 0, 0, 0);
            xI4[dt] = __builtin_amdgcn_mfma_f32_16x16x32_bf16(pi, vr, xI4[dt], 0, 0, 0);
            xI4[dt] = __builtin_amdgcn_mfma_f32_16x16x32_bf16(pr, vi, xI4[dt], 0, 0, 0);
        }
    }

    #pragma unroll
    for (int dt = 0; dt < 4; ++dt) {
        #pragma unroll
        for (int r = 0; r < 4; ++r) {
            const int c = wv * 16 + hi * 4 + r;
            const size_t o = (((size_t)(b * 64 + c) * 256) + t) * 256 + h * 64 + dt * 16 + l15;
            Xr[o] = f2bf(xR4[dt][r]);
            Xi[o] = f2bf(xI4[dt][r]);
        }
    }
}

// ---------------- Stage 3: complex output projection (BK=32, double-buffered, all-glds16) --
__global__ __launch_bounds__(512, 4)
void oproj_mfma(const unsigned short* __restrict__ Xr_g, const unsigned short* __restrict__ Xi_g,
                const unsigned short* __restrict__ wimg,
                const float* __restrict__ bo_r, const float* __restrict__ bo_i,
                float* __restrict__ outr, float* __restrict__ outi)
{
    __shared__ __align__(16) unsigned short SH[32768];

    const int tid = threadIdx.x;
    const int lane = tid & 63, wv = tid >> 6;
    const int l15 = lane & 15, hi = lane >> 4;
    const int wm = (wv >> 2) * 64, wn = (wv & 3) * 32;
    const int m0 = blockIdx.x * 128;
    const int nb = blockIdx.y;

    const unsigned short* wr_img = wimg + nb * 32768;
    const unsigned short* wi_img = wr_img + 65536;

    const int xrow = tid >> 2;     // 0..127
    const int xss  = tid & 3;
    const int xslot = xss ^ ((xrow >> 1) & 3);

    f32x4 accR[4][2] = {}, accI[4][2] = {};

    auto loadX = [&](int s, int buf) {
        const size_t so = (size_t)(m0 + xrow) * 256 + s * 32 + xslot * 8;
        glds16(Xr_g + so, &SH[buf * 16384 + tid * 8]);
        glds16(Xi_g + so, &SH[buf * 16384 + 4096 + tid * 8]);
    };
    auto loadW = [&](int s, int buf) {
        glds16(wr_img + s * 4096 + tid * 8, &SH[buf * 16384 + 8192 + tid * 8]);
        glds16(wi_img + s * 4096 + tid * 8, &SH[buf * 16384 + 12288 + tid * 8]);
    };

    loadX(0, 0); loadW(0, 0);
    __syncthreads();

    for (int s = 0; s < 8; ++s) {
        const int b = s & 1;
        if (s < 7) { loadX(s + 1, b ^ 1); loadW(s + 1, b ^ 1); }
        const unsigned short* Ar = &SH[b * 16384];
        const unsigned short* Ai = Ar + 4096;
        const unsigned short* Wr = Ar + 8192;
        const unsigned short* Wi = Ar + 12288;
        bfrag ar[4], ai[4], nai[4];
        #pragma unroll
        for (int mf = 0; mf < 4; ++mf) {
            const int m = wm + mf * 16 + l15;
            const int idx = m * 32 + ((hi ^ ((m >> 1) & 3)) << 3);
            ar[mf] = *(const bfrag*)&Ar[idx];
            ai[mf] = *(const bfrag*)&Ai[idx];
            nai[mf] = negf(ai[mf]);
        }
        #pragma unroll
        for (int nf = 0; nf < 2; ++nf) {
            const int n = wn + nf * 16 + l15;
            const int idx = n * 32 + ((hi ^ ((n >> 1) & 3)) << 3);
            const bfrag brf = *(const bfrag*)&Wr[idx];
            const bfrag bif = *(const bfrag*)&Wi[idx];
            #pragma unroll
            for (int mf = 0; mf < 4; ++mf) {
                accR[mf][nf] = __builtin_amdgcn_mfma_f32_16x16x32_bf16(ar[mf], brf, accR[mf][nf], 0, 0, 0);
                accR[mf][nf] = __builtin_amdgcn_mfma_f32_16x16x32_bf16(nai[mf], bif, accR[mf][nf], 0, 0, 0);
                accI[mf][nf] = __builtin_amdgcn_mfma_f32_16x16x32_bf16(ai[mf], brf, accI[mf][nf], 0, 0, 0);
                accI[mf][nf] = __builtin_amdgcn_mfma_f32_16x16x32_bf16(ar[mf], bif, accI[mf][nf], 0, 0, 0);
            }
        }
        __syncthreads();
    }

    const int rowL = (lane >> 4) << 2;
    #pragma unroll
    for (int nf = 0; nf < 2; ++nf) {
        const int n = nb * 128 + wn + nf * 16 + l15;
        const float vbr = bo_r[n], vbi = bo_i[n];
        const float addR = vbr - vbi, addI = vbr + vbi;
        #pragma unroll
        for (int mf = 0; mf < 4; ++mf) {
            const int mb = m0 + wm + mf * 16 + rowL;
            #pragma unroll
            for (int r = 0; r < 4; ++r) {
                const size_t o = (size_t)(mb + r) * 256 + n;
                outr[o] = accR[mf][nf][r] + addR;
                outi[o] = accI[mf][nf][r] + addI;
            }
        }
    }
}

extern "C" void kernel_launch(void* const* d_in, const int* in_sizes, int n_in,
                              void* d_out, int out_size, void* d_ws, size_t ws_size,
                              hipStream_t stream)
{
    (void)in_sizes; (void)n_in; (void)out_size; (void)ws_size;
    const float* q_r = (const float*)d_in[0];
    const float* q_i = (const float*)d_in[1];
    const float* k_r = (const float*)d_in[2];
    const float* k_i = (const float*)d_in[3];
    const float* v_r = (const float*)d_in[4];
    const float* v_i = (const float*)d_in[5];
    const int* mask = (const int*)d_in[6];
    const float* wq_r = (const float*)d_in[7];
    const float* wq_i = (const float*)d_in[8];
    const float* bq_r = (const float*)d_in[9];
    const float* bq_i = (const float*)d_in[10];
    const float* wk_r = (const float*)d_in[11];
    const float* wk_i = (const float*)d_in[12];
    const float* bk_r = (const float*)d_in[13];
    const float* bk_i = (const float*)d_in[14];
    const float* wv_r = (const float*)d_in[15];
    const float* wv_i = (const float*)d_in[16];
    const float* bv_r = (const float*)d_in[17];
    const float* bv_i = (const float*)d_in[18];
    const float* wo_r = (const float*)d_in[19];
    const float* wo_i = (const float*)d_in[20];
    const float* bo_r = (const float*)d_in[21];
    const float* bo_i = (const float*)d_in[22];

    const size_t TS = 16777216;
    unsigned short* ws = (unsigned short*)d_ws;
    unsigned short* Q = ws;                      // Qr,Qi,Kr,Ki,Vr,Vi: 6 x TS
    unsigned short* Xr = ws + 6 * TS;
    unsigned short* Xi = ws + 7 * TS;
    unsigned short* wimg_qkv = ws + 6 * TS;      // overlaid on X region (dead until attn)
    unsigned short* wimg_o = ws;                 // overlaid on Q region (dead after attn)

    wprep_kernel<<<dim3(32, 6), 256, 0, stream>>>(wq_r, wq_i, wk_r, wk_i, wv_r, wv_i, wimg_qkv);
    proj_mfma<<<dim3(512, 2, 3), 512, 0, stream>>>(q_r, q_i, k_r, k_i, v_r, v_i, wimg_qkv,
                                                   bq_r, bq_i, bk_r, bk_i, bv_r, bv_i, ws);
    attn_mfma<<<dim3(4096), 256, 0, stream>>>(Q, Q + TS, Q + 2 * TS, Q + 3 * TS,
                                              Q + 4 * TS, Q + 5 * TS, mask, Xr, Xi);
    wprep_kernel<<<dim3(32, 2), 256, 0, stream>>>(wo_r, wo_i, wo_r, wo_r, wo_r, wo_r, wimg_o);
    oproj_mfma<<<dim3(512, 2), 512, 0, stream>>>(Xr, Xi, wimg_o, bo_r, bo_i,
                                                 (float*)d_out, (float*)d_out + TS);
}

// Round 7
// 392.230 us; speedup vs baseline: 1.4337x; 1.4337x over previous
//
#include <hip/hip_runtime.h>
#include <hip/hip_bf16.h>
#include <cstddef>

#define MIN_VALUE_F (-3.402823466e38f)

// B=4, C=64, T=256, D=256, H=4, DK=64, OUT=256, M = B*C*T = 65536

typedef __attribute__((ext_vector_type(8))) __bf16 bfrag;    // MFMA A/B operand (4 VGPR)
typedef __attribute__((ext_vector_type(4))) float f32x4;     // MFMA C/D operand

__device__ __forceinline__ float bf2f(unsigned int u) {
    union { unsigned int i; float f; } v; v.i = u << 16; return v.f;
}
__device__ __forceinline__ unsigned short f2bf(float f) {
    union { float f; unsigned int i; } v; v.f = f;
    return (unsigned short)((v.i + 0x7fffu + ((v.i >> 16) & 1u)) >> 16);
}
__device__ __forceinline__ unsigned int cvt2(float a, float b) {
    __hip_bfloat16 lo = __float2bfloat16(a);
    __hip_bfloat16 hi = __float2bfloat16(b);
    union { __hip_bfloat16 h[2]; unsigned int u; } x;
    x.h[0] = lo; x.h[1] = hi;
    return x.u;
}
__device__ __forceinline__ bfrag negf(bfrag v) {
    union { bfrag b; unsigned int u[4]; } x; x.b = v;
    #pragma unroll
    for (int i = 0; i < 4; ++i) x.u[i] ^= 0x80008000u;
    return x.b;
}

typedef __attribute__((address_space(3))) void lds_void_t;
typedef const __attribute__((address_space(1))) void gmem_void_t;
__device__ __forceinline__ void glds16(const void* g, void* l) {
    __builtin_amdgcn_global_load_lds((gmem_void_t*)g, (lds_void_t*)l, 16, 0, 0);
}

// fragment read from XOR-swizzled row-major 64x64 bf16 tile (row stride 64 ushorts) [attn]
__device__ __forceinline__ bfrag rdfrag(const unsigned short* arr, int row, int slot) {
    const int s = slot ^ (row & 7);
    return *(const bfrag*)&arr[row * 64 + s * 8];
}

// ---------------- Weight prepass: f32 (K=256,N=256) -> bf16 pre-swizzled images ----
// Layout per matrix (65536 ush): [nt(4)][s(8)][n(64)][ss(4)][j(8)]
// content(ss) = source k-slot (ss ^ ((n>>1)&3)); global k = s*32 + slot*8 + j; col = nt*64+n.
__global__ __launch_bounds__(256)
void wprep_kernel(const float* __restrict__ w0, const float* __restrict__ w1,
                  const float* __restrict__ w2, const float* __restrict__ w3,
                  const float* __restrict__ w4, const float* __restrict__ w5,
                  unsigned short* __restrict__ dst)
{
    const int my = blockIdx.y;
    const float* wsrc[6] = {w0, w1, w2, w3, w4, w5};
    const float* w = wsrc[my];
    const int cid = blockIdx.x * 256 + threadIdx.x;   // 0..8191 chunks (16B each)
    const int ss = cid & 3;
    const int n  = (cid >> 2) & 63;
    const int s  = (cid >> 8) & 7;
    const int nt = (cid >> 11) & 3;
    const int nn = nt * 64 + n;
    const int kb = s * 32 + ((ss ^ ((n >> 1) & 3)) << 3);
    unsigned int p[4];
    #pragma unroll
    for (int jj = 0; jj < 4; ++jj) {
        const float a = w[(size_t)(kb + 2 * jj) * 256 + nn];
        const float b = w[(size_t)(kb + 2 * jj + 1) * 256 + nn];
        p[jj] = cvt2(a, b);
    }
    uint4 q; q.x = p[0]; q.y = p[1]; q.z = p[2]; q.w = p[3];
    *(uint4*)&dst[(size_t)my * 65536 + (size_t)cid * 8] = q;
}

// ---------------- Stage 1: complex QKV projection via MFMA ----------------
// 64x64 tile, BK=32, 8 K-steps, 4 waves (wave 32x32), 16 KB LDS, reg-staged A & W.
// 4 independent blocks/CU -> cross-block TLP hides load latency and barrier stalls.
// LDS (ushorts): A_r[0,2048) A_i[2048,4096) W_r[4096,6144) W_i[6144,8192).
__global__ __launch_bounds__(256, 4)
void proj_mfma(const float* __restrict__ xq_r, const float* __restrict__ xq_i,
               const float* __restrict__ xk_r, const float* __restrict__ xk_i,
               const float* __restrict__ xv_r, const float* __restrict__ xv_i,
               const unsigned short* __restrict__ wimg,
               const float* __restrict__ bq_r, const float* __restrict__ bq_i,
               const float* __restrict__ bk_r, const float* __restrict__ bk_i,
               const float* __restrict__ bv_r, const float* __restrict__ bv_i,
               unsigned short* __restrict__ ws_out)
{
    __shared__ __align__(16) unsigned short SH[8192];   // 16 KB

    const int pz = blockIdx.z;
    const float *xr, *xi, *br_, *bi_;
    if (pz == 0)      { xr = xq_r; xi = xq_i; br_ = bq_r; bi_ = bq_i; }
    else if (pz == 1) { xr = xk_r; xi = xk_i; br_ = bk_r; bi_ = bk_i; }
    else              { xr = xv_r; xi = xv_i; br_ = bv_r; bi_ = bv_i; }
    unsigned short* outr = ws_out + (size_t)pz * 2 * 16777216;
    unsigned short* outi = outr + 16777216;

    const int tid = threadIdx.x;
    const int lane = tid & 63, wv = tid >> 6;
    const int l15 = lane & 15, hi = lane >> 4;
    const int wm = (wv >> 1) * 32, wn = (wv & 1) * 32;
    const int ny = blockIdx.x;          // n-tile 0..3 == head
    const int m0 = blockIdx.y * 64;

    const unsigned short* wr_img = wimg + (size_t)pz * 131072 + ny * 16384;
    const unsigned short* wi_img = wr_img + 65536;

    unsigned short* As_r = SH;
    unsigned short* As_i = SH + 2048;
    unsigned short* Ws_r = SH + 4096;
    unsigned short* Ws_i = SH + 6144;

    // A staging: 64 rows x 32 k f32 x2; thread: row tid>>2, 8 consecutive floats at (tid&3)*8
    const int arow = tid >> 2;
    const int apos = tid & 3;
    const int asw = apos ^ ((arow >> 1) & 3);
    const int aidx = arow * 32 + (asw << 3);
    float4 fr0, fr1, fi0, fi1;
    uint4 wbr, wbi;

    f32x4 accR[2][2] = {}, accI[2][2] = {};

    auto load_step = [&](int s) {
        const size_t o = (size_t)(m0 + arow) * 256 + s * 32 + apos * 8;
        fr0 = *(const float4*)(xr + o);
        fr1 = *(const float4*)(xr + o + 4);
        fi0 = *(const float4*)(xi + o);
        fi1 = *(const float4*)(xi + o + 4);
        wbr = *(const uint4*)(wr_img + s * 2048 + tid * 8);
        wbi = *(const uint4*)(wi_img + s * 2048 + tid * 8);
    };
    auto write_stage = [&]() {
        uint4 p, q;
        p.x = cvt2(fr0.x, fr0.y); p.y = cvt2(fr0.z, fr0.w);
        p.z = cvt2(fr1.x, fr1.y); p.w = cvt2(fr1.z, fr1.w);
        q.x = cvt2(fi0.x, fi0.y); q.y = cvt2(fi0.z, fi0.w);
        q.z = cvt2(fi1.x, fi1.y); q.w = cvt2(fi1.z, fi1.w);
        *(uint4*)&As_r[aidx] = p;
        *(uint4*)&As_i[aidx] = q;
        *(uint4*)&Ws_r[tid * 8] = wbr;
        *(uint4*)&Ws_i[tid * 8] = wbi;
    };

    load_step(0);
    write_stage();
    __syncthreads();

    for (int s = 0; s < 8; ++s) {
        if (s < 7) load_step(s + 1);       // issue early; consumed after the MFMA phase
        bfrag ar[2], ai[2], nai[2];
        #pragma unroll
        for (int mf = 0; mf < 2; ++mf) {
            const int m = wm + mf * 16 + l15;
            const int idx = m * 32 + ((hi ^ ((m >> 1) & 3)) << 3);
            ar[mf] = *(const bfrag*)&As_r[idx];
            ai[mf] = *(const bfrag*)&As_i[idx];
            nai[mf] = negf(ai[mf]);
        }
        #pragma unroll
        for (int nf = 0; nf < 2; ++nf) {
            const int n = wn + nf * 16 + l15;
            const int idx = n * 32 + ((hi ^ ((n >> 1) & 3)) << 3);
            const bfrag brf = *(const bfrag*)&Ws_r[idx];
            const bfrag bif = *(const bfrag*)&Ws_i[idx];
            #pragma unroll
            for (int mf = 0; mf < 2; ++mf) {
                accR[mf][nf] = __builtin_amdgcn_mfma_f32_16x16x32_bf16(ar[mf], brf, accR[mf][nf], 0, 0, 0);
                accR[mf][nf] = __builtin_amdgcn_mfma_f32_16x16x32_bf16(nai[mf], bif, accR[mf][nf], 0, 0, 0);
                accI[mf][nf] = __builtin_amdgcn_mfma_f32_16x16x32_bf16(ai[mf], brf, accI[mf][nf], 0, 0, 0);
                accI[mf][nf] = __builtin_amdgcn_mfma_f32_16x16x32_bf16(ar[mf], bif, accI[mf][nf], 0, 0, 0);
            }
        }
        __syncthreads();                    // waves done reading LDS (lgkm only, no vmem drain)
        if (s < 7) { write_stage(); __syncthreads(); }
    }

    // ---- epilogue: bias, stage 64x64 bf16 tile (r @0, i @4096), coalesced store
    const int bc = m0 >> 8, b = bc >> 6, c = bc & 63, t0 = m0 & 255;
    #pragma unroll
    for (int nf = 0; nf < 2; ++nf) {
        const int n_loc = wn + nf * 16 + l15;
        const int n_glob = ny * 64 + n_loc;
        const float vbr = br_[n_glob], vbi = bi_[n_glob];
        const float addR = vbr - vbi, addI = vbr + vbi;
        #pragma unroll
        for (int mf = 0; mf < 2; ++mf) {
            #pragma unroll
            for (int r = 0; r < 4; ++r) {
                const int m_loc = wm + mf * 16 + hi * 4 + r;
                SH[m_loc * 64 + n_loc] = f2bf(accR[mf][nf][r] + addR);
                SH[4096 + m_loc * 64 + n_loc] = f2bf(accI[mf][nf][r] + addI);
            }
        }
    }
    __syncthreads();
    const int h = ny;
    #pragma unroll
    for (int p = 0; p < 2; ++p) {
        const int tr = (tid >> 3) + p * 32;
        const int dk = (tid & 7) * 8;
        const int L = tr * 64 + dk;
        const size_t g = (((size_t)(b * 4 + h) * 256 + (t0 + tr)) * 64 + c) * 64 + dk;
        *(uint4*)&outr[g] = *(const uint4*)&SH[L];
        *(uint4*)&outi[g] = *(const uint4*)&SH[4096 + L];
    }
}

// ---------------- Stage 2: fused complex attention per (b,h,t), MFMA (unchanged) ------
__global__ __launch_bounds__(256)
void attn_mfma(const unsigned short* __restrict__ Qg_r, const unsigned short* __restrict__ Qg_i,
               const unsigned short* __restrict__ Kg_r, const unsigned short* __restrict__ Kg_i,
               const unsigned short* __restrict__ Vg_r, const unsigned short* __restrict__ Vg_i,
               const int* __restrict__ mask,
               unsigned short* __restrict__ Xr, unsigned short* __restrict__ Xi)
{
    __shared__ __align__(16) unsigned short sQr[4096], sQi[4096];   // Q, then P
    __shared__ __align__(16) unsigned short sKr[4096], sKi[4096];
    __shared__ __align__(16) unsigned short sVr[4608], sVi[4608];   // V^T, rows padded to 72
    __shared__ int smask[64];

    const int bht = blockIdx.x;
    const int b = bht >> 10;
    const int h = (bht >> 8) & 3;
    const int t = bht & 255;
    const size_t base = (size_t)bht * 4096;
    const int tid = threadIdx.x;
    const int lane = tid & 63, wv = tid >> 6;
    const int l15 = lane & 15, hi = lane >> 4;

    const int ep = (lane & 31) * 2;
    const int dch = wv * 2 + (lane >> 5);
    const unsigned short* vr0p = Vg_r + base + (size_t)ep * 64 + dch * 8;
    const unsigned short* vi0p = Vg_i + base + (size_t)ep * 64 + dch * 8;
    const uint4 vr0 = *(const uint4*)vr0p;
    const uint4 vr1 = *(const uint4*)(vr0p + 64);
    const uint4 vi0 = *(const uint4*)vi0p;
    const uint4 vi1 = *(const uint4*)(vi0p + 64);

    #pragma unroll
    for (int i = 0; i < 2; ++i) {
        const int ch = wv * 128 + i * 64 + lane;
        const int r = ch >> 3, cg = ch & 7;
        const int so = r * 64 + ((cg ^ (r & 7)) << 3);
        const int dofs = (wv * 128 + i * 64) << 3;
        glds16(Qg_r + base + so, &sQr[dofs]);
        glds16(Qg_i + base + so, &sQi[dofs]);
        glds16(Kg_r + base + so, &sKr[dofs]);
        glds16(Kg_i + base + so, &sKi[dofs]);
    }
    if (tid < 64) smask[tid] = mask[b * 64 + tid];

    {
        union { uint4 v; unsigned short s[8]; } ar0, ar1, ai0, ai1;
        ar0.v = vr0; ar1.v = vr1; ai0.v = vi0; ai1.v = vi1;
        #pragma unroll
        for (int j = 0; j < 8; ++j) {
            const int d = dch * 8 + j;
            *(unsigned int*)&sVr[d * 72 + ep] = (unsigned)ar0.s[j] | ((unsigned)ar1.s[j] << 16);
            *(unsigned int*)&sVi[d * 72 + ep] = (unsigned)ai0.s[j] | ((unsigned)ai1.s[j] << 16);
        }
    }
    __syncthreads();

    const int cq = wv * 16 + l15;
    f32x4 aR[4] = {}, aI[4] = {};
    #pragma unroll
    for (int ks = 0; ks < 2; ++ks) {
        const int slot = ks * 4 + hi;
        const bfrag qr = rdfrag(sQr, cq, slot);
        const bfrag qi = rdfrag(sQi, cq, slot);
        const bfrag nqi = negf(qi);
        #pragma unroll
        for (int et = 0; et < 4; ++et) {
            const int re = et * 16 + l15;
            const bfrag kr = rdfrag(sKr, re, slot);
            const bfrag ki = rdfrag(sKi, re, slot);
            aR[et] = __builtin_amdgcn_mfma_f32_16x16x32_bf16(kr, qr, aR[et], 0, 0, 0);
            aR[et] = __builtin_amdgcn_mfma_f32_16x16x32_bf16(ki, qi, aR[et], 0, 0, 0);
            aI[et] = __builtin_amdgcn_mfma_f32_16x16x32_bf16(ki, qr, aI[et], 0, 0, 0);
            aI[et] = __builtin_amdgcn_mfma_f32_16x16x32_bf16(kr, nqi, aI[et], 0, 0, 0);
        }
    }
    __syncthreads();

    const float scale = 0.125f;
    float amp[4][4], ex[4][4];
    float mx = MIN_VALUE_F;
    #pragma unroll
    for (int et = 0; et < 4; ++et) {
        #pragma unroll
        for (int r = 0; r < 4; ++r) {
            const float sr = aR[et][r] * scale;
            const float si = aI[et][r] * scale;
            float a = sqrtf(fmaf(sr, sr, si * si));
            if (smask[et * 16 + hi * 4 + r] == 0) a = MIN_VALUE_F;
            amp[et][r] = a;
            mx = fmaxf(mx, a);
        }
    }
    mx = fmaxf(mx, __shfl_xor(mx, 16, 64));
    mx = fmaxf(mx, __shfl_xor(mx, 32, 64));
    float sm = 0.f;
    #pragma unroll
    for (int et = 0; et < 4; ++et) {
        #pragma unroll
        for (int r = 0; r < 4; ++r) {
            const float e_ = expf(amp[et][r] - mx);
            ex[et][r] = e_; sm += e_;
        }
    }
    sm += __shfl_xor(sm, 16, 64);
    sm += __shfl_xor(sm, 32, 64);

    #pragma unroll
    for (int et = 0; et < 4; ++et) {
        float pr[4], pi[4];
        #pragma unroll
        for (int r = 0; r < 4; ++r) {
            const float w = ex[et][r] * __builtin_amdgcn_rcpf(sm * amp[et][r]);
            pr[r] = w * (aR[et][r] * scale);
            pi[r] = w * (aI[et][r] * scale);
        }
        const int pidx = cq * 64 + ((et * 16 + hi * 4) ^ ((cq & 7) << 3));
        uint2 ur, ui;
        ur.x = cvt2(pr[0], pr[1]); ur.y = cvt2(pr[2], pr[3]);
        ui.x = cvt2(pi[0], pi[1]); ui.y = cvt2(pi[2], pi[3]);
        *(uint2*)&sQr[pidx] = ur;
        *(uint2*)&sQi[pidx] = ui;
    }
    __syncthreads();

    f32x4 xR4[4] = {}, xI4[4] = {};
    #pragma unroll
    for (int ks = 0; ks < 2; ++ks) {
        const int slot = ks * 4 + hi;
        const bfrag pr = rdfrag(sQr, cq, slot);
        const bfrag pi = rdfrag(sQi, cq, slot);
        const bfrag npi = negf(pi);
        #pragma unroll
        for (int dt = 0; dt < 4; ++dt) {
            const int rd = dt * 16 + l15;
            const bfrag vr = *(const bfrag*)&sVr[rd * 72 + ks * 32 + hi * 8];
            const bfrag vi = *(const bfrag*)&sVi[rd * 72 + ks * 32 + hi * 8];
            xR4[dt] = __builtin_amdgcn_mfma_f32_16x16x32_bf16(pr, vr, xR4[dt], 0, 0, 0);
            xR4[dt] = __builtin_amdgcn_mfma_f32_16x16x32_bf16(npi, vi, xR4[dt], 0, 0, 0);
            xI4[dt] = __builtin_amdgcn_mfma_f32_16x16x32_bf16(pi, vr, xI4[dt], 0, 0, 0);
            xI4[dt] = __builtin_amdgcn_mfma_f32_16x16x32_bf16(pr, vi, xI4[dt], 0, 0, 0);
        }
    }

    #pragma unroll
    for (int dt = 0; dt < 4; ++dt) {
        #pragma unroll
        for (int r = 0; r < 4; ++r) {
            const int c = wv * 16 + hi * 4 + r;
            const size_t o = (((size_t)(b * 64 + c) * 256) + t) * 256 + h * 64 + dt * 16 + l15;
            Xr[o] = f2bf(xR4[dt][r]);
            Xi[o] = f2bf(xI4[dt][r]);
        }
    }
}

// ---------------- Stage 3: complex output projection (64x64 tile, reg-staged) ----------
__global__ __launch_bounds__(256, 4)
void oproj_mfma(const unsigned short* __restrict__ Xr_g, const unsigned short* __restrict__ Xi_g,
                const unsigned short* __restrict__ wimg,
                const float* __restrict__ bo_r, const float* __restrict__ bo_i,
                float* __restrict__ outr, float* __restrict__ outi)
{
    __shared__ __align__(16) unsigned short SH[8192];

    const int tid = threadIdx.x;
    const int lane = tid & 63, wv = tid >> 6;
    const int l15 = lane & 15, hi = lane >> 4;
    const int wm = (wv >> 1) * 32, wn = (wv & 1) * 32;
    const int ny = blockIdx.x;
    const int m0 = blockIdx.y * 64;

    const unsigned short* wr_img = wimg + ny * 16384;
    const unsigned short* wi_img = wr_img + 65536;

    unsigned short* As_r = SH;
    unsigned short* As_i = SH + 2048;
    unsigned short* Ws_r = SH + 4096;
    unsigned short* Ws_i = SH + 6144;

    const int xrow = tid >> 2;
    const int xslot = tid & 3;
    const int xsw = xslot ^ ((xrow >> 1) & 3);
    const int xidx = xrow * 32 + xslot * 8;
    uint4 xbr, xbi, wbr, wbi;

    f32x4 accR[2][2] = {}, accI[2][2] = {};

    auto load_step = [&](int s) {
        const size_t o = (size_t)(m0 + xrow) * 256 + s * 32 + xsw * 8;
        xbr = *(const uint4*)(Xr_g + o);
        xbi = *(const uint4*)(Xi_g + o);
        wbr = *(const uint4*)(wr_img + s * 2048 + tid * 8);
        wbi = *(const uint4*)(wi_img + s * 2048 + tid * 8);
    };
    auto write_stage = [&]() {
        *(uint4*)&As_r[xidx] = xbr;
        *(uint4*)&As_i[xidx] = xbi;
        *(uint4*)&Ws_r[tid * 8] = wbr;
        *(uint4*)&Ws_i[tid * 8] = wbi;
    };

    load_step(0);
    write_stage();
    __syncthreads();

    for (int s = 0; s < 8; ++s) {
        if (s < 7) load_step(s + 1);
        bfrag ar[2], ai[2], nai[2];
        #pragma unroll
        for (int mf = 0; mf < 2; ++mf) {
            const int m = wm + mf * 16 + l15;
            const int idx = m * 32 + ((hi ^ ((m >> 1) & 3)) << 3);
            ar[mf] = *(const bfrag*)&As_r[idx];
            ai[mf] = *(const bfrag*)&As_i[idx];
            nai[mf] = negf(ai[mf]);
        }
        #pragma unroll
        for (int nf = 0; nf < 2; ++nf) {
            const int n = wn + nf * 16 + l15;
            const int idx = n * 32 + ((hi ^ ((n >> 1) & 3)) << 3);
            const bfrag brf = *(const bfrag*)&Ws_r[idx];
            const bfrag bif = *(const bfrag*)&Ws_i[idx];
            #pragma unroll
            for (int mf = 0; mf < 2; ++mf) {
                accR[mf][nf] = __builtin_amdgcn_mfma_f32_16x16x32_bf16(ar[mf], brf, accR[mf][nf], 0, 0, 0);
                accR[mf][nf] = __builtin_amdgcn_mfma_f32_16x16x32_bf16(nai[mf], bif, accR[mf][nf], 0, 0, 0);
                accI[mf][nf] = __builtin_amdgcn_mfma_f32_16x16x32_bf16(ai[mf], brf, accI[mf][nf], 0, 0, 0);
                accI[mf][nf] = __builtin_amdgcn_mfma_f32_16x16x32_bf16(ar[mf], bif, accI[mf][nf], 0, 0, 0);
            }
        }
        __syncthreads();
        if (s < 7) { write_stage(); __syncthreads(); }
    }

    #pragma unroll
    for (int nf = 0; nf < 2; ++nf) {
        const int n = ny * 64 + wn + nf * 16 + l15;
        const float vbr = bo_r[n], vbi = bo_i[n];
        const float addR = vbr - vbi, addI = vbr + vbi;
        #pragma unroll
        for (int mf = 0; mf < 2; ++mf) {
            #pragma unroll
            for (int r = 0; r < 4; ++r) {
                const size_t o = (size_t)(m0 + wm + mf * 16 + hi * 4 + r) * 256 + n;
                outr[o] = accR[mf][nf][r] + addR;
                outi[o] = accI[mf][nf][r] + addI;
            }
        }
    }
}

extern "C" void kernel_launch(void* const* d_in, const int* in_sizes, int n_in,
                              void* d_out, int out_size, void* d_ws, size_t ws_size,
                              hipStream_t stream)
{
    (void)in_sizes; (void)n_in; (void)out_size; (void)ws_size;
    const float* q_r = (const float*)d_in[0];
    const float* q_i = (const float*)d_in[1];
    const float* k_r = (const float*)d_in[2];
    const float* k_i = (const float*)d_in[3];
    const float* v_r = (const float*)d_in[4];
    const float* v_i = (const float*)d_in[5];
    const int* mask = (const int*)d_in[6];
    const float* wq_r = (const float*)d_in[7];
    const float* wq_i = (const float*)d_in[8];
    const float* bq_r = (const float*)d_in[9];
    const float* bq_i = (const float*)d_in[10];
    const float* wk_r = (const float*)d_in[11];
    const float* wk_i = (const float*)d_in[12];
    const float* bk_r = (const float*)d_in[13];
    const float* bk_i = (const float*)d_in[14];
    const float* wv_r = (const float*)d_in[15];
    const float* wv_i = (const float*)d_in[16];
    const float* bv_r = (const float*)d_in[17];
    const float* bv_i = (const float*)d_in[18];
    const float* wo_r = (const float*)d_in[19];
    const float* wo_i = (const float*)d_in[20];
    const float* bo_r = (const float*)d_in[21];
    const float* bo_i = (const float*)d_in[22];

    const size_t TS = 16777216;
    unsigned short* ws = (unsigned short*)d_ws;
    unsigned short* Q = ws;                      // Qr,Qi,Kr,Ki,Vr,Vi: 6 x TS
    unsigned short* Xr = ws + 6 * TS;
    unsigned short* Xi = ws + 7 * TS;
    unsigned short* wimg_qkv = ws + 6 * TS;      // overlaid on X region (dead until attn)
    unsigned short* wimg_o = ws;                 // overlaid on Q region (dead after attn)

    wprep_kernel<<<dim3(32, 6), 256, 0, stream>>>(wq_r, wq_i, wk_r, wk_i, wv_r, wv_i, wimg_qkv);
    proj_mfma<<<dim3(4, 1024, 3), 256, 0, stream>>>(q_r, q_i, k_r, k_i, v_r, v_i, wimg_qkv,
                                                    bq_r, bq_i, bk_r, bk_i, bv_r, bv_i, ws);
    attn_mfma<<<dim3(4096), 256, 0, stream>>>(Q, Q + TS, Q + 2 * TS, Q + 3 * TS,
                                              Q + 4 * TS, Q + 5 * TS, mask, Xr, Xi);
    wprep_kernel<<<dim3(32, 2), 256, 0, stream>>>(wo_r, wo_i, wo_r, wo_r, wo_r, wo_r, wimg_o);
    oproj_mfma<<<dim3(4, 1024), 256, 0, stream>>>(Xr, Xi, wimg_o, bo_r, bo_i,
                                                  (float*)d_out, (float*)d_out + TS);
}

// Round 8
// 330.277 us; speedup vs baseline: 1.7026x; 1.1876x over previous
//
#include <hip/hip_runtime.h>
#include <hip/hip_bf16.h>
#include <cstddef>

#define MIN_VALUE_F (-3.402823466e38f)

// B=4, C=64, T=256, D=256, H=4, DK=64, OUT=256, M = B*C*T = 65536

typedef __attribute__((ext_vector_type(8))) __bf16 bfrag;    // MFMA A/B operand (4 VGPR)
typedef __attribute__((ext_vector_type(4))) float f32x4;     // MFMA C/D operand

__device__ __forceinline__ float bf2f(unsigned int u) {
    union { unsigned int i; float f; } v; v.i = u << 16; return v.f;
}
__device__ __forceinline__ unsigned short f2bf(float f) {
    union { float f; unsigned int i; } v; v.f = f;
    return (unsigned short)((v.i + 0x7fffu + ((v.i >> 16) & 1u)) >> 16);
}
__device__ __forceinline__ unsigned int cvt2(float a, float b) {
    __hip_bfloat16 lo = __float2bfloat16(a);
    __hip_bfloat16 hi = __float2bfloat16(b);
    union { __hip_bfloat16 h[2]; unsigned int u; } x;
    x.h[0] = lo; x.h[1] = hi;
    return x.u;
}
__device__ __forceinline__ bfrag negf(bfrag v) {
    union { bfrag b; unsigned int u[4]; } x; x.b = v;
    #pragma unroll
    for (int i = 0; i < 4; ++i) x.u[i] ^= 0x80008000u;
    return x.b;
}

typedef __attribute__((address_space(3))) void lds_void_t;
typedef const __attribute__((address_space(1))) void gmem_void_t;
__device__ __forceinline__ void glds16(const void* g, void* l) {
    __builtin_amdgcn_global_load_lds((gmem_void_t*)g, (lds_void_t*)l, 16, 0, 0);
}

// fragment read from XOR-swizzled row-major 64x64 bf16 tile (row stride 64 ushorts) [attn]
__device__ __forceinline__ bfrag rdfrag(const unsigned short* arr, int row, int slot) {
    const int s = slot ^ (row & 7);
    return *(const bfrag*)&arr[row * 64 + s * 8];
}

// ---------------- Weight prepass: f32 (K=256,N=256) -> bf16 pre-swizzled images ----
// Layout per matrix (65536 ush): [nt(4)][s(8)][n(64)][ss(4)][j(8)]
// content(ss) = source k-slot (ss ^ ((n>>1)&3)); global k = s*32 + slot*8 + j; col = nt*64+n.
__global__ __launch_bounds__(256)
void wprep_kernel(const float* __restrict__ w0, const float* __restrict__ w1,
                  const float* __restrict__ w2, const float* __restrict__ w3,
                  const float* __restrict__ w4, const float* __restrict__ w5,
                  unsigned short* __restrict__ dst)
{
    const int my = blockIdx.y;
    const float* wsrc[6] = {w0, w1, w2, w3, w4, w5};
    const float* w = wsrc[my];
    const int cid = blockIdx.x * 256 + threadIdx.x;   // 0..8191 chunks (16B each)
    const int ss = cid & 3;
    const int n  = (cid >> 2) & 63;
    const int s  = (cid >> 8) & 7;
    const int nt = (cid >> 11) & 3;
    const int nn = nt * 64 + n;
    const int kb = s * 32 + ((ss ^ ((n >> 1) & 3)) << 3);
    unsigned int p[4];
    #pragma unroll
    for (int jj = 0; jj < 4; ++jj) {
        const float a = w[(size_t)(kb + 2 * jj) * 256 + nn];
        const float b = w[(size_t)(kb + 2 * jj + 1) * 256 + nn];
        p[jj] = cvt2(a, b);
    }
    uint4 q; q.x = p[0]; q.y = p[1]; q.z = p[2]; q.w = p[3];
    *(uint4*)&dst[(size_t)my * 65536 + (size_t)cid * 8] = q;
}

// ---------------- Stage 1: complex QKV projection via MFMA ----------------
// 64x64 tile, BK=32, 8 K-steps, 4 waves (wave 32x32), double-buffered 2x16KB LDS,
// reg-staged A & W, ONE barrier per step. XCD-chunked 1D grid: the 4 n-tiles
// sharing an A-stripe land on the SAME XCD consecutively -> A re-reads are L2 hits.
// Per buf (ushorts): A_r[0,2048) A_i[2048,4096) W_r[4096,6144) W_i[6144,8192).
__global__ __launch_bounds__(256, 4)
void proj_mfma(const float* __restrict__ xq_r, const float* __restrict__ xq_i,
               const float* __restrict__ xk_r, const float* __restrict__ xk_i,
               const float* __restrict__ xv_r, const float* __restrict__ xv_i,
               const unsigned short* __restrict__ wimg,
               const float* __restrict__ bq_r, const float* __restrict__ bq_i,
               const float* __restrict__ bk_r, const float* __restrict__ bk_i,
               const float* __restrict__ bv_r, const float* __restrict__ bv_i,
               unsigned short* __restrict__ ws_out)
{
    __shared__ __align__(16) unsigned short SH[16384];   // 32 KB (2 bufs)

    // XCD-chunked bijective swizzle: 12288 blocks = 8 XCDs x 1536
    const int bid = blockIdx.x;
    const int work = (bid & 7) * 1536 + (bid >> 3);
    const int ny = work & 3;                 // n-tile (head), innermost -> same XCD
    const int rest = work >> 2;              // 0..3071
    const int m0 = (rest & 1023) * 64;
    const int pz = rest >> 10;

    const float *xr, *xi, *br_, *bi_;
    if (pz == 0)      { xr = xq_r; xi = xq_i; br_ = bq_r; bi_ = bq_i; }
    else if (pz == 1) { xr = xk_r; xi = xk_i; br_ = bk_r; bi_ = bk_i; }
    else              { xr = xv_r; xi = xv_i; br_ = bv_r; bi_ = bv_i; }
    unsigned short* outr = ws_out + (size_t)pz * 2 * 16777216;
    unsigned short* outi = outr + 16777216;

    const int tid = threadIdx.x;
    const int lane = tid & 63, wv = tid >> 6;
    const int l15 = lane & 15, hi = lane >> 4;
    const int wm = (wv >> 1) * 32, wn = (wv & 1) * 32;

    const unsigned short* wr_img = wimg + (size_t)pz * 131072 + ny * 16384;
    const unsigned short* wi_img = wr_img + 65536;

    // A staging: 64 rows x 32 k f32 x2; thread: row tid>>2, 8 consecutive floats at (tid&3)*8
    const int arow = tid >> 2;
    const int apos = tid & 3;
    const int asw = apos ^ ((arow >> 1) & 3);
    const int aidx = arow * 32 + (asw << 3);
    float4 fr0, fr1, fi0, fi1;
    uint4 wbr, wbi;

    f32x4 accR[2][2] = {}, accI[2][2] = {};

    auto load_step = [&](int s) {
        const size_t o = (size_t)(m0 + arow) * 256 + s * 32 + apos * 8;
        fr0 = *(const float4*)(xr + o);
        fr1 = *(const float4*)(xr + o + 4);
        fi0 = *(const float4*)(xi + o);
        fi1 = *(const float4*)(xi + o + 4);
        wbr = *(const uint4*)(wr_img + s * 2048 + tid * 8);
        wbi = *(const uint4*)(wi_img + s * 2048 + tid * 8);
    };
    auto write_stage = [&](int buf) {
        unsigned short* B = SH + buf * 8192;
        uint4 p, q;
        p.x = cvt2(fr0.x, fr0.y); p.y = cvt2(fr0.z, fr0.w);
        p.z = cvt2(fr1.x, fr1.y); p.w = cvt2(fr1.z, fr1.w);
        q.x = cvt2(fi0.x, fi0.y); q.y = cvt2(fi0.z, fi0.w);
        q.z = cvt2(fi1.x, fi1.y); q.w = cvt2(fi1.z, fi1.w);
        *(uint4*)&B[aidx] = p;
        *(uint4*)&B[2048 + aidx] = q;
        *(uint4*)&B[4096 + tid * 8] = wbr;
        *(uint4*)&B[6144 + tid * 8] = wbi;
    };

    load_step(0);
    write_stage(0);
    __syncthreads();

    for (int s = 0; s < 8; ++s) {
        const int b = s & 1;
        if (s < 7) load_step(s + 1);       // issue early; latency hides under MFMAs
        const unsigned short* As_r = SH + b * 8192;
        const unsigned short* As_i = As_r + 2048;
        const unsigned short* Ws_r = As_r + 4096;
        const unsigned short* Ws_i = As_r + 6144;
        bfrag ar[2], ai[2], nai[2];
        #pragma unroll
        for (int mf = 0; mf < 2; ++mf) {
            const int m = wm + mf * 16 + l15;
            const int idx = m * 32 + ((hi ^ ((m >> 1) & 3)) << 3);
            ar[mf] = *(const bfrag*)&As_r[idx];
            ai[mf] = *(const bfrag*)&As_i[idx];
            nai[mf] = negf(ai[mf]);
        }
        #pragma unroll
        for (int nf = 0; nf < 2; ++nf) {
            const int n = wn + nf * 16 + l15;
            const int idx = n * 32 + ((hi ^ ((n >> 1) & 3)) << 3);
            const bfrag brf = *(const bfrag*)&Ws_r[idx];
            const bfrag bif = *(const bfrag*)&Ws_i[idx];
            #pragma unroll
            for (int mf = 0; mf < 2; ++mf) {
                accR[mf][nf] = __builtin_amdgcn_mfma_f32_16x16x32_bf16(ar[mf], brf, accR[mf][nf], 0, 0, 0);
                accR[mf][nf] = __builtin_amdgcn_mfma_f32_16x16x32_bf16(nai[mf], bif, accR[mf][nf], 0, 0, 0);
                accI[mf][nf] = __builtin_amdgcn_mfma_f32_16x16x32_bf16(ai[mf], brf, accI[mf][nf], 0, 0, 0);
                accI[mf][nf] = __builtin_amdgcn_mfma_f32_16x16x32_bf16(ar[mf], bif, accI[mf][nf], 0, 0, 0);
            }
        }
        if (s < 7) write_stage(b ^ 1);     // other buffer: no race with this step's reads
        __syncthreads();
    }

    // ---- epilogue: bias, stage 64x64 bf16 tile (r @0, i @4096), coalesced store
    const int bc = m0 >> 8, b = bc >> 6, c = bc & 63, t0 = m0 & 255;
    #pragma unroll
    for (int nf = 0; nf < 2; ++nf) {
        const int n_loc = wn + nf * 16 + l15;
        const int n_glob = ny * 64 + n_loc;
        const float vbr = br_[n_glob], vbi = bi_[n_glob];
        const float addR = vbr - vbi, addI = vbr + vbi;
        #pragma unroll
        for (int mf = 0; mf < 2; ++mf) {
            #pragma unroll
            for (int r = 0; r < 4; ++r) {
                const int m_loc = wm + mf * 16 + hi * 4 + r;
                SH[m_loc * 64 + n_loc] = f2bf(accR[mf][nf][r] + addR);
                SH[4096 + m_loc * 64 + n_loc] = f2bf(accI[mf][nf][r] + addI);
            }
        }
    }
    __syncthreads();
    const int h = ny;
    #pragma unroll
    for (int p = 0; p < 2; ++p) {
        const int tr = (tid >> 3) + p * 32;
        const int dk = (tid & 7) * 8;
        const int L = tr * 64 + dk;
        const size_t g = (((size_t)(b * 4 + h) * 256 + (t0 + tr)) * 64 + c) * 64 + dk;
        *(uint4*)&outr[g] = *(const uint4*)&SH[L];
        *(uint4*)&outi[g] = *(const uint4*)&SH[4096 + L];
    }
}

// ---------------- Stage 2: fused complex attention per (b,h,t), MFMA (unchanged) ------
__global__ __launch_bounds__(256)
void attn_mfma(const unsigned short* __restrict__ Qg_r, const unsigned short* __restrict__ Qg_i,
               const unsigned short* __restrict__ Kg_r, const unsigned short* __restrict__ Kg_i,
               const unsigned short* __restrict__ Vg_r, const unsigned short* __restrict__ Vg_i,
               const int* __restrict__ mask,
               unsigned short* __restrict__ Xr, unsigned short* __restrict__ Xi)
{
    __shared__ __align__(16) unsigned short sQr[4096], sQi[4096];   // Q, then P
    __shared__ __align__(16) unsigned short sKr[4096], sKi[4096];
    __shared__ __align__(16) unsigned short sVr[4608], sVi[4608];   // V^T, rows padded to 72
    __shared__ int smask[64];

    const int bht = blockIdx.x;
    const int b = bht >> 10;
    const int h = (bht >> 8) & 3;
    const int t = bht & 255;
    const size_t base = (size_t)bht * 4096;
    const int tid = threadIdx.x;
    const int lane = tid & 63, wv = tid >> 6;
    const int l15 = lane & 15, hi = lane >> 4;

    const int ep = (lane & 31) * 2;
    const int dch = wv * 2 + (lane >> 5);
    const unsigned short* vr0p = Vg_r + base + (size_t)ep * 64 + dch * 8;
    const unsigned short* vi0p = Vg_i + base + (size_t)ep * 64 + dch * 8;
    const uint4 vr0 = *(const uint4*)vr0p;
    const uint4 vr1 = *(const uint4*)(vr0p + 64);
    const uint4 vi0 = *(const uint4*)vi0p;
    const uint4 vi1 = *(const uint4*)(vi0p + 64);

    #pragma unroll
    for (int i = 0; i < 2; ++i) {
        const int ch = wv * 128 + i * 64 + lane;
        const int r = ch >> 3, cg = ch & 7;
        const int so = r * 64 + ((cg ^ (r & 7)) << 3);
        const int dofs = (wv * 128 + i * 64) << 3;
        glds16(Qg_r + base + so, &sQr[dofs]);
        glds16(Qg_i + base + so, &sQi[dofs]);
        glds16(Kg_r + base + so, &sKr[dofs]);
        glds16(Kg_i + base + so, &sKi[dofs]);
    }
    if (tid < 64) smask[tid] = mask[b * 64 + tid];

    {
        union { uint4 v; unsigned short s[8]; } ar0, ar1, ai0, ai1;
        ar0.v = vr0; ar1.v = vr1; ai0.v = vi0; ai1.v = vi1;
        #pragma unroll
        for (int j = 0; j < 8; ++j) {
            const int d = dch * 8 + j;
            *(unsigned int*)&sVr[d * 72 + ep] = (unsigned)ar0.s[j] | ((unsigned)ar1.s[j] << 16);
            *(unsigned int*)&sVi[d * 72 + ep] = (unsigned)ai0.s[j] | ((unsigned)ai1.s[j] << 16);
        }
    }
    __syncthreads();

    const int cq = wv * 16 + l15;
    f32x4 aR[4] = {}, aI[4] = {};
    #pragma unroll
    for (int ks = 0; ks < 2; ++ks) {
        const int slot = ks * 4 + hi;
        const bfrag qr = rdfrag(sQr, cq, slot);
        const bfrag qi = rdfrag(sQi, cq, slot);
        const bfrag nqi = negf(qi);
        #pragma unroll
        for (int et = 0; et < 4; ++et) {
            const int re = et * 16 + l15;
            const bfrag kr = rdfrag(sKr, re, slot);
            const bfrag ki = rdfrag(sKi, re, slot);
            aR[et] = __builtin_amdgcn_mfma_f32_16x16x32_bf16(kr, qr, aR[et], 0, 0, 0);
            aR[et] = __builtin_amdgcn_mfma_f32_16x16x32_bf16(ki, qi, aR[et], 0, 0, 0);
            aI[et] = __builtin_amdgcn_mfma_f32_16x16x32_bf16(ki, qr, aI[et], 0, 0, 0);
            aI[et] = __builtin_amdgcn_mfma_f32_16x16x32_bf16(kr, nqi, aI[et], 0, 0, 0);
        }
    }
    __syncthreads();

    const float scale = 0.125f;
    float amp[4][4], ex[4][4];
    float mx = MIN_VALUE_F;
    #pragma unroll
    for (int et = 0; et < 4; ++et) {
        #pragma unroll
        for (int r = 0; r < 4; ++r) {
            const float sr = aR[et][r] * scale;
            const float si = aI[et][r] * scale;
            float a = sqrtf(fmaf(sr, sr, si * si));
            if (smask[et * 16 + hi * 4 + r] == 0) a = MIN_VALUE_F;
            amp[et][r] = a;
            mx = fmaxf(mx, a);
        }
    }
    mx = fmaxf(mx, __shfl_xor(mx, 16, 64));
    mx = fmaxf(mx, __shfl_xor(mx, 32, 64));
    float sm = 0.f;
    #pragma unroll
    for (int et = 0; et < 4; ++et) {
        #pragma unroll
        for (int r = 0; r < 4; ++r) {
            const float e_ = expf(amp[et][r] - mx);
            ex[et][r] = e_; sm += e_;
        }
    }
    sm += __shfl_xor(sm, 16, 64);
    sm += __shfl_xor(sm, 32, 64);

    #pragma unroll
    for (int et = 0; et < 4; ++et) {
        float pr[4], pi[4];
        #pragma unroll
        for (int r = 0; r < 4; ++r) {
            const float w = ex[et][r] * __builtin_amdgcn_rcpf(sm * amp[et][r]);
            pr[r] = w * (aR[et][r] * scale);
            pi[r] = w * (aI[et][r] * scale);
        }
        const int pidx = cq * 64 + ((et * 16 + hi * 4) ^ ((cq & 7) << 3));
        uint2 ur, ui;
        ur.x = cvt2(pr[0], pr[1]); ur.y = cvt2(pr[2], pr[3]);
        ui.x = cvt2(pi[0], pi[1]); ui.y = cvt2(pi[2], pi[3]);
        *(uint2*)&sQr[pidx] = ur;
        *(uint2*)&sQi[pidx] = ui;
    }
    __syncthreads();

    f32x4 xR4[4] = {}, xI4[4] = {};
    #pragma unroll
    for (int ks = 0; ks < 2; ++ks) {
        const int slot = ks * 4 + hi;
        const bfrag pr = rdfrag(sQr, cq, slot);
        const bfrag pi = rdfrag(sQi, cq, slot);
        const bfrag npi = negf(pi);
        #pragma unroll
        for (int dt = 0; dt < 4; ++dt) {
            const int rd = dt * 16 + l15;
            const bfrag vr = *(const bfrag*)&sVr[rd * 72 + ks * 32 + hi * 8];
            const bfrag vi = *(const bfrag*)&sVi[rd * 72 + ks * 32 + hi * 8];
            xR4[dt] = __builtin_amdgcn_mfma_f32_16x16x32_bf16(pr, vr, xR4[dt], 0, 0, 0);
            xR4[dt] = __builtin_amdgcn_mfma_f32_16x16x32_bf16(npi, vi, xR4[dt], 0, 0, 0);
            xI4[dt] = __builtin_amdgcn_mfma_f32_16x16x32_bf16(pi, vr, xI4[dt], 0, 0, 0);
            xI4[dt] = __builtin_amdgcn_mfma_f32_16x16x32_bf16(pr, vi, xI4[dt], 0, 0, 0);
        }
    }

    #pragma unroll
    for (int dt = 0; dt < 4; ++dt) {
        #pragma unroll
        for (int r = 0; r < 4; ++r) {
            const int c = wv * 16 + hi * 4 + r;
            const size_t o = (((size_t)(b * 64 + c) * 256) + t) * 256 + h * 64 + dt * 16 + l15;
            Xr[o] = f2bf(xR4[dt][r]);
            Xi[o] = f2bf(xI4[dt][r]);
        }
    }
}

// ---------------- Stage 3: complex output projection (64x64, dbuf, XCD-chunked) --------
__global__ __launch_bounds__(256, 4)
void oproj_mfma(const unsigned short* __restrict__ Xr_g, const unsigned short* __restrict__ Xi_g,
                const unsigned short* __restrict__ wimg,
                const float* __restrict__ bo_r, const float* __restrict__ bo_i,
                float* __restrict__ outr, float* __restrict__ outi)
{
    __shared__ __align__(16) unsigned short SH[16384];

    // XCD-chunked bijective swizzle: 4096 blocks = 8 XCDs x 512
    const int bid = blockIdx.x;
    const int work = (bid & 7) * 512 + (bid >> 3);
    const int ny = work & 3;
    const int m0 = (work >> 2) * 64;

    const int tid = threadIdx.x;
    const int lane = tid & 63, wv = tid >> 6;
    const int l15 = lane & 15, hi = lane >> 4;
    const int wm = (wv >> 1) * 32, wn = (wv & 1) * 32;

    const unsigned short* wr_img = wimg + ny * 16384;
    const unsigned short* wi_img = wr_img + 65536;

    const int xrow = tid >> 2;
    const int xslot = tid & 3;
    const int xsw = xslot ^ ((xrow >> 1) & 3);
    const int xidx = xrow * 32 + xslot * 8;
    uint4 xbr, xbi, wbr, wbi;

    f32x4 accR[2][2] = {}, accI[2][2] = {};

    auto load_step = [&](int s) {
        const size_t o = (size_t)(m0 + xrow) * 256 + s * 32 + xsw * 8;
        xbr = *(const uint4*)(Xr_g + o);
        xbi = *(const uint4*)(Xi_g + o);
        wbr = *(const uint4*)(wr_img + s * 2048 + tid * 8);
        wbi = *(const uint4*)(wi_img + s * 2048 + tid * 8);
    };
    auto write_stage = [&](int buf) {
        unsigned short* B = SH + buf * 8192;
        *(uint4*)&B[xidx] = xbr;
        *(uint4*)&B[2048 + xidx] = xbi;
        *(uint4*)&B[4096 + tid * 8] = wbr;
        *(uint4*)&B[6144 + tid * 8] = wbi;
    };

    load_step(0);
    write_stage(0);
    __syncthreads();

    for (int s = 0; s < 8; ++s) {
        const int b = s & 1;
        if (s < 7) load_step(s + 1);
        const unsigned short* As_r = SH + b * 8192;
        const unsigned short* As_i = As_r + 2048;
        const unsigned short* Ws_r = As_r + 4096;
        const unsigned short* Ws_i = As_r + 6144;
        bfrag ar[2], ai[2], nai[2];
        #pragma unroll
        for (int mf = 0; mf < 2; ++mf) {
            const int m = wm + mf * 16 + l15;
            const int idx = m * 32 + ((hi ^ ((m >> 1) & 3)) << 3);
            ar[mf] = *(const bfrag*)&As_r[idx];
            ai[mf] = *(const bfrag*)&As_i[idx];
            nai[mf] = negf(ai[mf]);
        }
        #pragma unroll
        for (int nf = 0; nf < 2; ++nf) {
            const int n = wn + nf * 16 + l15;
            const int idx = n * 32 + ((hi ^ ((n >> 1) & 3)) << 3);
            const bfrag brf = *(const bfrag*)&Ws_r[idx];
            const bfrag bif = *(const bfrag*)&Ws_i[idx];
            #pragma unroll
            for (int mf = 0; mf < 2; ++mf) {
                accR[mf][nf] = __builtin_amdgcn_mfma_f32_16x16x32_bf16(ar[mf], brf, accR[mf][nf], 0, 0, 0);
                accR[mf][nf] = __builtin_amdgcn_mfma_f32_16x16x32_bf16(nai[mf], bif, accR[mf][nf], 0, 0, 0);
                accI[mf][nf] = __builtin_amdgcn_mfma_f32_16x16x32_bf16(ai[mf], brf, accI[mf][nf], 0, 0, 0);
                accI[mf][nf] = __builtin_amdgcn_mfma_f32_16x16x32_bf16(ar[mf], bif, accI[mf][nf], 0, 0, 0);
            }
        }
        if (s < 7) write_stage(b ^ 1);
        __syncthreads();
    }

    #pragma unroll
    for (int nf = 0; nf < 2; ++nf) {
        const int n = ny * 64 + wn + nf * 16 + l15;
        const float vbr = bo_r[n], vbi = bo_i[n];
        const float addR = vbr - vbi, addI = vbr + vbi;
        #pragma unroll
        for (int mf = 0; mf < 2; ++mf) {
            #pragma unroll
            for (int r = 0; r < 4; ++r) {
                const size_t o = (size_t)(m0 + wm + mf * 16 + hi * 4 + r) * 256 + n;
                outr[o] = accR[mf][nf][r] + addR;
                outi[o] = accI[mf][nf][r] + addI;
            }
        }
    }
}

extern "C" void kernel_launch(void* const* d_in, const int* in_sizes, int n_in,
                              void* d_out, int out_size, void* d_ws, size_t ws_size,
                              hipStream_t stream)
{
    (void)in_sizes; (void)n_in; (void)out_size; (void)ws_size;
    const float* q_r = (const float*)d_in[0];
    const float* q_i = (const float*)d_in[1];
    const float* k_r = (const float*)d_in[2];
    const float* k_i = (const float*)d_in[3];
    const float* v_r = (const float*)d_in[4];
    const float* v_i = (const float*)d_in[5];
    const int* mask = (const int*)d_in[6];
    const float* wq_r = (const float*)d_in[7];
    const float* wq_i = (const float*)d_in[8];
    const float* bq_r = (const float*)d_in[9];
    const float* bq_i = (const float*)d_in[10];
    const float* wk_r = (const float*)d_in[11];
    const float* wk_i = (const float*)d_in[12];
    const float* bk_r = (const float*)d_in[13];
    const float* bk_i = (const float*)d_in[14];
    const float* wv_r = (const float*)d_in[15];
    const float* wv_i = (const float*)d_in[16];
    const float* bv_r = (const float*)d_in[17];
    const float* bv_i = (const float*)d_in[18];
    const float* wo_r = (const float*)d_in[19];
    const float* wo_i = (const float*)d_in[20];
    const float* bo_r = (const float*)d_in[21];
    const float* bo_i = (const float*)d_in[22];

    const size_t TS = 16777216;
    unsigned short* ws = (unsigned short*)d_ws;
    unsigned short* Q = ws;                      // Qr,Qi,Kr,Ki,Vr,Vi: 6 x TS
    unsigned short* Xr = ws + 6 * TS;
    unsigned short* Xi = ws + 7 * TS;
    unsigned short* wimg_qkv = ws + 6 * TS;      // overlaid on X region (dead until attn)
    unsigned short* wimg_o = ws;                 // overlaid on Q region (dead after attn)

    wprep_kernel<<<dim3(32, 6), 256, 0, stream>>>(wq_r, wq_i, wk_r, wk_i, wv_r, wv_i, wimg_qkv);
    proj_mfma<<<dim3(12288), 256, 0, stream>>>(q_r, q_i, k_r, k_i, v_r, v_i, wimg_qkv,
                                               bq_r, bq_i, bk_r, bk_i, bv_r, bv_i, ws);
    attn_mfma<<<dim3(4096), 256, 0, stream>>>(Q, Q + TS, Q + 2 * TS, Q + 3 * TS,
                                              Q + 4 * TS, Q + 5 * TS, mask, Xr, Xi);
    wprep_kernel<<<dim3(32, 2), 256, 0, stream>>>(wo_r, wo_i, wo_r, wo_r, wo_r, wo_r, wimg_o);
    oproj_mfma<<<dim3(4096), 256, 0, stream>>>(Xr, Xi, wimg_o, bo_r, bo_i,
                                               (float*)d_out, (float*)d_out + TS);
}